// Round 10
// baseline (58.876 us; speedup 1.0000x reference)
//
#include <hip/hip_runtime.h>

// LoKr via layout-chained MFMA (f16 inputs, fp32 accum), zero LDS.
// Chain (contract n -> m -> r -> s), per batch row b, Xb = reshape(x[b], 64m x 64n):
//   D1[m][s] = sum_n  Xb[m][n]   w2b[n][s]    (16 mfma, A=X float4-loaded)
//   D2[r][s] = sum_m  w1b[m][r]  D1[m][s]     ( 4 mfma)
//   D3[s][l] = sum_r  D2[r][s]   w1a[r][l]/16 ( 4 mfma)
//   yT[k][l] = sum_s  w2a^T[k][s] D3[s][l]    (16 mfma, A=W2A, B=D3)
// Junction rule (validated R7/R9): C-frag(row R, col C) == A-frag(M=C,K=R)
// == B-frag(N=C,K=R) of the next mfma. R10: S4 operands swapped so lane regs
// hold 4 consecutive k -> float4 stores; stores are NON-TEMPORAL so the 134MB
// output stream doesn't evict x from L3 (x fits: 134 < 256MB) across replays.

typedef __fp16 h2 __attribute__((ext_vector_type(2)));
typedef __fp16 h4 __attribute__((ext_vector_type(4)));
typedef float  f4 __attribute__((ext_vector_type(4)));

__device__ __forceinline__ h4 pack4(float a, float b, float c, float d) {
    h2 lo = __builtin_amdgcn_cvt_pkrtz(a, b);
    h2 hi = __builtin_amdgcn_cvt_pkrtz(c, d);
    h4 r;
    r[0] = lo[0]; r[1] = lo[1]; r[2] = hi[0]; r[3] = hi[1];
    return r;
}

#define MFMA16(a, b, c) __builtin_amdgcn_mfma_f32_16x16x16f16((a), (b), (c), 0, 0, 0)

#define ROWS 4   // rows per wave; 512 blocks x 4 waves x 4 rows = 8192

__global__ __launch_bounds__(256) void lokr_kernel(
    const float* __restrict__ x,
    const float* __restrict__ w1_a,   // (16, 64) [r][l]
    const float* __restrict__ w1_b,   // (64, 16) [m][r]
    const float* __restrict__ w2_a,   // (16, 64) [s][k]
    const float* __restrict__ w2_b,   // (64, 16) [n][s]
    float* __restrict__ out)
{
    const int lane = threadIdx.x & 63;
    const int g    = lane >> 4;        // 0..3
    const int c    = lane & 15;        // 0..15
    const int gw   = blockIdx.x * 4 + (threadIdx.x >> 6);
    const size_t b0 = (size_t)gw * ROWS;

    // ---- static weight fragments (once per wave, L2-hot) ----
    // W2B[nk]:  B-frag S1 (K=n,N=s): j -> w2_b[n=nk*16+g*4+j][s=c]
    // W1BT[mt]: A-frag S2 (M=r,K=m): j -> w1b^T[r=c][m=mt*16+g*4+j]
    // W1A[lt]:  B-frag S3 (K=r,N=l): j -> w1_a[r=g*4+j][l=lt*16+c] * (1/16)
    // W2A[kt]:  dual-role frag: j -> w2_a[s=g*4+j][k=kt*16+c]
    //           (A-frag(M=k,K=s) of S4 == B-frag(K=s,N=k) -- same registers)
    h4 W2B[4], W1BT[4], W1A[4], W2A[4];
#pragma unroll
    for (int t = 0; t < 4; ++t) {
        const int kb = t * 16 + g * 4;
        W2B[t]  = pack4(w2_b[(kb+0)*16 + c], w2_b[(kb+1)*16 + c],
                        w2_b[(kb+2)*16 + c], w2_b[(kb+3)*16 + c]);
        W1BT[t] = pack4(w1_b[(kb+0)*16 + c], w1_b[(kb+1)*16 + c],
                        w1_b[(kb+2)*16 + c], w1_b[(kb+3)*16 + c]);
        W1A[t]  = pack4(w1_a[(g*4+0)*64 + t*16 + c] * 0.0625f,
                        w1_a[(g*4+1)*64 + t*16 + c] * 0.0625f,
                        w1_a[(g*4+2)*64 + t*16 + c] * 0.0625f,
                        w1_a[(g*4+3)*64 + t*16 + c] * 0.0625f);
        W2A[t]  = pack4(w2_a[(g*4+0)*64 + t*16 + c], w2_a[(g*4+1)*64 + t*16 + c],
                        w2_a[(g*4+2)*64 + t*16 + c], w2_a[(g*4+3)*64 + t*16 + c]);
    }

    const f4 zero = {0.f, 0.f, 0.f, 0.f};
    const float* xp = x + b0 * 4096;
    const int xoff = c * 64 + g * 4;   // + mt*1024 + nk*16

    f4 xf[16];
    h4 XA[16];

    // prologue: row-0 loads, 16 float4 in flight
#pragma unroll
    for (int mt = 0; mt < 4; ++mt)
#pragma unroll
        for (int nk = 0; nk < 4; ++nk)
            xf[mt * 4 + nk] = *(const f4*)&xp[mt * 1024 + nk * 16 + xoff];

#pragma unroll
    for (int rr = 0; rr < ROWS; ++rr) {
        // cvt current row (drains its loads), freeing xf for the next row
#pragma unroll
        for (int i = 0; i < 16; ++i)
            XA[i] = pack4(xf[i][0], xf[i][1], xf[i][2], xf[i][3]);

        if (rr + 1 < ROWS) {
#pragma unroll
            for (int mt = 0; mt < 4; ++mt)
#pragma unroll
                for (int nk = 0; nk < 4; ++nk)
                    xf[mt * 4 + nk] = *(const f4*)&xp[(size_t)(rr + 1) * 4096 +
                                                     mt * 1024 + nk * 16 + xoff];
        }
        __builtin_amdgcn_sched_barrier(0);   // next-row loads stay above compute

        // ---- S1: D1[mt] (row m, col s) = sum_nk mfma(XA, W2B) ----
        f4 D1[4];
#pragma unroll
        for (int mt = 0; mt < 4; ++mt) {
            f4 a = zero;
#pragma unroll
            for (int nk = 0; nk < 4; ++nk)
                a = MFMA16(XA[mt * 4 + nk], W2B[nk], a);
            D1[mt] = a;
        }
        // ---- S2: D2 (row r, col s) = sum_mt mfma(W1BT[mt], D1H[mt]) ----
        f4 d2 = zero;
#pragma unroll
        for (int mt = 0; mt < 4; ++mt)
            d2 = MFMA16(W1BT[mt], pack4(D1[mt][0], D1[mt][1], D1[mt][2], D1[mt][3]), d2);
        h4 D2H = pack4(d2[0], d2[1], d2[2], d2[3]);
        // ---- S3: D3[lt] (row s, col l) = mfma(D2H, W1A[lt]) ----
        h4 D3H[4];
#pragma unroll
        for (int lt = 0; lt < 4; ++lt) {
            f4 d3 = MFMA16(D2H, W1A[lt], zero);
            D3H[lt] = pack4(d3[0], d3[1], d3[2], d3[3]);
        }
        // ---- S4 (transposed): yT tile = mfma(A=W2A[kt], B=D3H[lt]) ----
        // C: row k=kt*16+g*4+reg, col l=lt*16+c -> out elem l*64+k: reg contiguous
        float* op = out + (b0 + rr) * 4096;
#pragma unroll
        for (int lt = 0; lt < 4; ++lt) {
#pragma unroll
            for (int kt = 0; kt < 4; ++kt) {
                f4 y = MFMA16(W2A[kt], D3H[lt], zero);
                __builtin_nontemporal_store(
                    y, reinterpret_cast<f4*>(op + (lt * 16 + c) * 64 + kt * 16 + g * 4));
            }
        }
    }
}

extern "C" void kernel_launch(void* const* d_in, const int* in_sizes, int n_in,
                              void* d_out, int out_size, void* d_ws, size_t ws_size,
                              hipStream_t stream) {
    const float* x    = (const float*)d_in[0];
    const float* w1_a = (const float*)d_in[1];
    const float* w1_b = (const float*)d_in[2];
    const float* w2_a = (const float*)d_in[3];
    const float* w2_b = (const float*)d_in[4];
    float* out = (float*)d_out;

    // 8192 rows / (4 waves * 4 rows/wave) = 512 blocks
    dim3 grid(512), block(256);
    hipLaunchKernelGGL(lokr_kernel, grid, block, 0, stream,
                       x, w1_a, w1_b, w2_a, w2_b, out);
}

// Round 11
// 49.474 us; speedup vs baseline: 1.1900x; 1.1900x over previous
//
#include <hip/hip_runtime.h>

// LoKr via layout-chained MFMA (f16 inputs, fp32 accum), zero LDS.
// Chain (contract n -> m -> r -> s), per batch row b, Xb = reshape(x[b], 64m x 64n):
//   D1[m][s] = sum_n  Xb[m][n]   w2b[n][s]    (16 mfma, A=X float4-loaded)
//   D2[r][s] = sum_m  w1b[m][r]  D1[m][s]     ( 4 mfma)
//   D3[s][l] = sum_r  D2[r][s]   w1a[r][l]/16 ( 4 mfma)
//   yT[k][l] = sum_s  w2a^T[k][s] D3[s][l]    (16 mfma, A=W2A, B=D3)
// Junction rule (validated R7/R9/R10): C-frag(row R, col C) == A-frag(M=C,K=R)
// == B-frag(N=C,K=R) of the next mfma -> whole chain stays in registers.
// R11: transposed S4 f4 stores kept; NON-TEMPORAL REVERTED (R10: WRITE_SIZE
// 131->170MB RMW amplification, dur +10us). Plain allocating stores coalesce
// 64B lane segments in L2. This is the R9 structure + f4 stores, ROWS=4.

typedef __fp16 h2 __attribute__((ext_vector_type(2)));
typedef __fp16 h4 __attribute__((ext_vector_type(4)));
typedef float  f4 __attribute__((ext_vector_type(4)));

__device__ __forceinline__ h4 pack4(float a, float b, float c, float d) {
    h2 lo = __builtin_amdgcn_cvt_pkrtz(a, b);
    h2 hi = __builtin_amdgcn_cvt_pkrtz(c, d);
    h4 r;
    r[0] = lo[0]; r[1] = lo[1]; r[2] = hi[0]; r[3] = hi[1];
    return r;
}

#define MFMA16(a, b, c) __builtin_amdgcn_mfma_f32_16x16x16f16((a), (b), (c), 0, 0, 0)

#define ROWS 4   // rows per wave; 512 blocks x 4 waves x 4 rows = 8192

__global__ __launch_bounds__(256) void lokr_kernel(
    const float* __restrict__ x,
    const float* __restrict__ w1_a,   // (16, 64) [r][l]
    const float* __restrict__ w1_b,   // (64, 16) [m][r]
    const float* __restrict__ w2_a,   // (16, 64) [s][k]
    const float* __restrict__ w2_b,   // (64, 16) [n][s]
    float* __restrict__ out)
{
    const int lane = threadIdx.x & 63;
    const int g    = lane >> 4;        // 0..3
    const int c    = lane & 15;        // 0..15
    const int gw   = blockIdx.x * 4 + (threadIdx.x >> 6);
    const size_t b0 = (size_t)gw * ROWS;

    // ---- static weight fragments (once per wave, L2-hot) ----
    // W2B[nk]:  B-frag S1 (K=n,N=s): j -> w2_b[n=nk*16+g*4+j][s=c]
    // W1BT[mt]: A-frag S2 (M=r,K=m): j -> w1b^T[r=c][m=mt*16+g*4+j]
    // W1A[lt]:  B-frag S3 (K=r,N=l): j -> w1_a[r=g*4+j][l=lt*16+c] * (1/16)
    // W2A[kt]:  A-frag S4 (M=k,K=s): j -> w2_a[s=g*4+j][k=kt*16+c]
    h4 W2B[4], W1BT[4], W1A[4], W2A[4];
#pragma unroll
    for (int t = 0; t < 4; ++t) {
        const int kb = t * 16 + g * 4;
        W2B[t]  = pack4(w2_b[(kb+0)*16 + c], w2_b[(kb+1)*16 + c],
                        w2_b[(kb+2)*16 + c], w2_b[(kb+3)*16 + c]);
        W1BT[t] = pack4(w1_b[(kb+0)*16 + c], w1_b[(kb+1)*16 + c],
                        w1_b[(kb+2)*16 + c], w1_b[(kb+3)*16 + c]);
        W1A[t]  = pack4(w1_a[(g*4+0)*64 + t*16 + c] * 0.0625f,
                        w1_a[(g*4+1)*64 + t*16 + c] * 0.0625f,
                        w1_a[(g*4+2)*64 + t*16 + c] * 0.0625f,
                        w1_a[(g*4+3)*64 + t*16 + c] * 0.0625f);
        W2A[t]  = pack4(w2_a[(g*4+0)*64 + t*16 + c], w2_a[(g*4+1)*64 + t*16 + c],
                        w2_a[(g*4+2)*64 + t*16 + c], w2_a[(g*4+3)*64 + t*16 + c]);
    }

    const f4 zero = {0.f, 0.f, 0.f, 0.f};
    const float* xp = x + b0 * 4096;
    const int xoff = c * 64 + g * 4;   // + mt*1024 + nk*16

    f4 xf[16];
    h4 XA[16];

    // prologue: row-0 loads, 16 float4 in flight
#pragma unroll
    for (int mt = 0; mt < 4; ++mt)
#pragma unroll
        for (int nk = 0; nk < 4; ++nk)
            xf[mt * 4 + nk] = *(const f4*)&xp[mt * 1024 + nk * 16 + xoff];

#pragma unroll
    for (int rr = 0; rr < ROWS; ++rr) {
        // cvt current row (drains its loads), freeing xf for the next row
#pragma unroll
        for (int i = 0; i < 16; ++i)
            XA[i] = pack4(xf[i][0], xf[i][1], xf[i][2], xf[i][3]);

        if (rr + 1 < ROWS) {
#pragma unroll
            for (int mt = 0; mt < 4; ++mt)
#pragma unroll
                for (int nk = 0; nk < 4; ++nk)
                    xf[mt * 4 + nk] = *(const f4*)&xp[(size_t)(rr + 1) * 4096 +
                                                     mt * 1024 + nk * 16 + xoff];
        }
        __builtin_amdgcn_sched_barrier(0);   // next-row loads stay above compute

        // ---- S1: D1[mt] (row m, col s) = sum_nk mfma(XA, W2B) ----
        f4 D1[4];
#pragma unroll
        for (int mt = 0; mt < 4; ++mt) {
            f4 a = zero;
#pragma unroll
            for (int nk = 0; nk < 4; ++nk)
                a = MFMA16(XA[mt * 4 + nk], W2B[nk], a);
            D1[mt] = a;
        }
        // ---- S2: D2 (row r, col s) = sum_mt mfma(W1BT[mt], D1H[mt]) ----
        f4 d2 = zero;
#pragma unroll
        for (int mt = 0; mt < 4; ++mt)
            d2 = MFMA16(W1BT[mt], pack4(D1[mt][0], D1[mt][1], D1[mt][2], D1[mt][3]), d2);
        h4 D2H = pack4(d2[0], d2[1], d2[2], d2[3]);
        // ---- S3: D3[lt] (row s, col l) = mfma(D2H, W1A[lt]) ----
        h4 D3H[4];
#pragma unroll
        for (int lt = 0; lt < 4; ++lt) {
            f4 d3 = MFMA16(D2H, W1A[lt], zero);
            D3H[lt] = pack4(d3[0], d3[1], d3[2], d3[3]);
        }
        // ---- S4 (transposed): yT tile = mfma(A=W2A[kt], B=D3H[lt]) ----
        // C: row k=kt*16+g*4+reg, col l=lt*16+c -> out elem l*64+k: reg contiguous
        float* op = out + (b0 + rr) * 4096;
#pragma unroll
        for (int lt = 0; lt < 4; ++lt) {
#pragma unroll
            for (int kt = 0; kt < 4; ++kt) {
                f4 y = MFMA16(W2A[kt], D3H[lt], zero);
                *reinterpret_cast<f4*>(op + (lt * 16 + c) * 64 + kt * 16 + g * 4) = y;
            }
        }
    }
}

extern "C" void kernel_launch(void* const* d_in, const int* in_sizes, int n_in,
                              void* d_out, int out_size, void* d_ws, size_t ws_size,
                              hipStream_t stream) {
    const float* x    = (const float*)d_in[0];
    const float* w1_a = (const float*)d_in[1];
    const float* w1_b = (const float*)d_in[2];
    const float* w2_a = (const float*)d_in[3];
    const float* w2_b = (const float*)d_in[4];
    float* out = (float*)d_out;

    // 8192 rows / (4 waves * 4 rows/wave) = 512 blocks
    dim3 grid(512), block(256);
    hipLaunchKernelGGL(lokr_kernel, grid, block, 0, stream,
                       x, w1_a, w1_b, w2_a, w2_b, out);
}

// Round 12
// 46.573 us; speedup vs baseline: 1.2642x; 1.0623x over previous
//
#include <hip/hip_runtime.h>

// LoKr via layout-chained MFMA (f16 inputs, fp32 accum).
// Chain (contract n -> m -> r -> s), per batch row b, Xb = reshape(x[b], 64m x 64n):
//   D1[m][s] = sum_n  Xb[m][n]   w2b[n][s]    (16 mfma, A=X float4-loaded)
//   D2[r][s] = sum_m  w1b[m][r]  D1[m][s]     ( 4 mfma)
//   D3[s][l] = sum_r  D2[r][s]   w1a[r][l]/16 ( 4 mfma)
//   yT[k][l] = sum_s  w2a^T[k][s] D3[s][l]    (16 mfma, A=W2A, B=D3)
// R12: y-tile staged in LDS (XOR swizzle phys = logical ^ ((row&7)<<2), keeps
// 16B alignment), then streamed as 16 wave-contiguous 1KB NON-TEMPORAL stores
// (full 128B-line coverage -> no RMW, unlike R10's 64B chunks). Goal: writes
// bypass L3 allocation so x (134MB < 256MB L3) stays resident across replays.
// Inverse swizzle applied to the GLOBAL address (bijective per row).

typedef __fp16 h2 __attribute__((ext_vector_type(2)));
typedef __fp16 h4 __attribute__((ext_vector_type(4)));
typedef float  f4 __attribute__((ext_vector_type(4)));

__device__ __forceinline__ h4 pack4(float a, float b, float c, float d) {
    h2 lo = __builtin_amdgcn_cvt_pkrtz(a, b);
    h2 hi = __builtin_amdgcn_cvt_pkrtz(c, d);
    h4 r;
    r[0] = lo[0]; r[1] = lo[1]; r[2] = hi[0]; r[3] = hi[1];
    return r;
}

#define MFMA16(a, b, c) __builtin_amdgcn_mfma_f32_16x16x16f16((a), (b), (c), 0, 0, 0)

#define WPB  4   // waves per block
#define ROWS 4   // rows per wave; 512 blocks x 4 waves x 4 rows = 8192

__global__ __launch_bounds__(256) void lokr_kernel(
    const float* __restrict__ x,
    const float* __restrict__ w1_a,   // (16, 64) [r][l]
    const float* __restrict__ w1_b,   // (64, 16) [m][r]
    const float* __restrict__ w2_a,   // (16, 64) [s][k]
    const float* __restrict__ w2_b,   // (64, 16) [n][s]
    float* __restrict__ out)
{
    __shared__ __align__(16) float sy[WPB][64][64];   // 64 KB: per-wave y-tile

    const int tid  = threadIdx.x;
    const int wave = tid >> 6;
    const int lane = tid & 63;
    const int g    = lane >> 4;        // 0..3
    const int c    = lane & 15;        // 0..15
    const int gw   = blockIdx.x * WPB + wave;
    const size_t b0 = (size_t)gw * ROWS;

    // ---- static weight fragments (once per wave, L2-hot) ----
    // W2B[nk]:  B-frag S1 (K=n,N=s): j -> w2_b[n=nk*16+g*4+j][s=c]
    // W1BT[mt]: A-frag S2 (M=r,K=m): j -> w1b^T[r=c][m=mt*16+g*4+j]
    // W1A[lt]:  B-frag S3 (K=r,N=l): j -> w1_a[r=g*4+j][l=lt*16+c] * (1/16)
    // W2A[kt]:  A-frag S4 (M=k,K=s): j -> w2_a[s=g*4+j][k=kt*16+c]
    h4 W2B[4], W1BT[4], W1A[4], W2A[4];
#pragma unroll
    for (int t = 0; t < 4; ++t) {
        const int kb = t * 16 + g * 4;
        W2B[t]  = pack4(w2_b[(kb+0)*16 + c], w2_b[(kb+1)*16 + c],
                        w2_b[(kb+2)*16 + c], w2_b[(kb+3)*16 + c]);
        W1BT[t] = pack4(w1_b[(kb+0)*16 + c], w1_b[(kb+1)*16 + c],
                        w1_b[(kb+2)*16 + c], w1_b[(kb+3)*16 + c]);
        W1A[t]  = pack4(w1_a[(g*4+0)*64 + t*16 + c] * 0.0625f,
                        w1_a[(g*4+1)*64 + t*16 + c] * 0.0625f,
                        w1_a[(g*4+2)*64 + t*16 + c] * 0.0625f,
                        w1_a[(g*4+3)*64 + t*16 + c] * 0.0625f);
        W2A[t]  = pack4(w2_a[(g*4+0)*64 + t*16 + c], w2_a[(g*4+1)*64 + t*16 + c],
                        w2_a[(g*4+2)*64 + t*16 + c], w2_a[(g*4+3)*64 + t*16 + c]);
    }

    const f4 zero = {0.f, 0.f, 0.f, 0.f};
    const float* xp = x + b0 * 4096;
    const int xoff = c * 64 + g * 4;   // + mt*1024 + nk*16
    float* syw = &sy[wave][0][0];

    f4 xf[16];
    h4 XA[16];

    // prologue: row-0 loads, 16 float4 in flight
#pragma unroll
    for (int mt = 0; mt < 4; ++mt)
#pragma unroll
        for (int nk = 0; nk < 4; ++nk)
            xf[mt * 4 + nk] = *(const f4*)&xp[mt * 1024 + nk * 16 + xoff];

#pragma unroll
    for (int rr = 0; rr < ROWS; ++rr) {
        // cvt current row (drains its loads), freeing xf for the next row
#pragma unroll
        for (int i = 0; i < 16; ++i)
            XA[i] = pack4(xf[i][0], xf[i][1], xf[i][2], xf[i][3]);

        if (rr + 1 < ROWS) {
#pragma unroll
            for (int mt = 0; mt < 4; ++mt)
#pragma unroll
                for (int nk = 0; nk < 4; ++nk)
                    xf[mt * 4 + nk] = *(const f4*)&xp[(size_t)(rr + 1) * 4096 +
                                                     mt * 1024 + nk * 16 + xoff];
        }
        __builtin_amdgcn_sched_barrier(0);   // next-row loads stay above compute

        // ---- S1: D1[mt] (row m, col s) = sum_nk mfma(XA, W2B) ----
        f4 D1[4];
#pragma unroll
        for (int mt = 0; mt < 4; ++mt) {
            f4 a = zero;
#pragma unroll
            for (int nk = 0; nk < 4; ++nk)
                a = MFMA16(XA[mt * 4 + nk], W2B[nk], a);
            D1[mt] = a;
        }
        // ---- S2: D2 (row r, col s) = sum_mt mfma(W1BT[mt], D1H[mt]) ----
        f4 d2 = zero;
#pragma unroll
        for (int mt = 0; mt < 4; ++mt)
            d2 = MFMA16(W1BT[mt], pack4(D1[mt][0], D1[mt][1], D1[mt][2], D1[mt][3]), d2);
        h4 D2H = pack4(d2[0], d2[1], d2[2], d2[3]);
        // ---- S3: D3[lt] (row s, col l) = mfma(D2H, W1A[lt]) ----
        h4 D3H[4];
#pragma unroll
        for (int lt = 0; lt < 4; ++lt) {
            f4 d3 = MFMA16(D2H, W1A[lt], zero);
            D3H[lt] = pack4(d3[0], d3[1], d3[2], d3[3]);
        }
        // ---- S4 (transposed): yT tile -> LDS, XOR-swizzled ----
        // C-frag: row k=kt*16+g*4+reg, col l=lt*16+c -> logical dword
        // L = (lt*16+c)*64 + kt*16 + g*4 (4 consecutive k). phys = L ^ ((c&7)<<2).
#pragma unroll
        for (int lt = 0; lt < 4; ++lt) {
#pragma unroll
            for (int kt = 0; kt < 4; ++kt) {
                f4 y = MFMA16(W2A[kt], D3H[lt], zero);
                const int L = (lt * 16 + c) * 64 + kt * 16 + g * 4;
                *(f4*)&syw[L ^ ((c & 7) << 2)] = y;   // ds_write_b128
            }
        }
        asm volatile("s_waitcnt lgkmcnt(0)" ::: "memory");  // tile visible wave-wide

        // ---- stream tile: 16 x 1KB wave-contiguous nt stores ----
        // lane reads phys p = i*256+lane*4 (linear b128, conflict-free);
        // logical = p ^ (((p>>6)&7)<<2); row(p>>6) = i*4 + (lane>>4).
        float* op = out + (b0 + rr) * 4096;
#pragma unroll
        for (int i = 0; i < 16; ++i) {
            const int p = i * 256 + lane * 4;
            f4 v = *(const f4*)&syw[p];
            const int L2 = p ^ ((((i * 4) + (lane >> 4)) & 7) << 2);
            __builtin_nontemporal_store(v, reinterpret_cast<f4*>(op + L2));
        }
    }
}

extern "C" void kernel_launch(void* const* d_in, const int* in_sizes, int n_in,
                              void* d_out, int out_size, void* d_ws, size_t ws_size,
                              hipStream_t stream) {
    const float* x    = (const float*)d_in[0];
    const float* w1_a = (const float*)d_in[1];
    const float* w1_b = (const float*)d_in[2];
    const float* w2_a = (const float*)d_in[3];
    const float* w2_b = (const float*)d_in[4];
    float* out = (float*)d_out;

    // 8192 rows / (4 waves * 4 rows/wave) = 512 blocks
    dim3 grid(512), block(256);
    hipLaunchKernelGGL(lokr_kernel, grid, block, 0, stream,
                       x, w1_a, w1_b, w2_a, w2_b, out);
}